// Round 4
// baseline (338.517 us; speedup 1.0000x reference)
//
#include <hip/hip_runtime.h>

// BinaryDense: out = sign(x) @ sign(w). x[8192,4096] f32, w[4096,4096] f32, out f32.
// fp4 e2m1 nibble encoding {-1,0,+1} = {0xA,0x0,0x2}; MX-scaled fp4 MFMA (scales=1.0).
// Round 7: A-direct-from-L1. R4-R6 showed the kernel is LDS-BW-bound (131 KB/half
// vs 85 B/cyc effective): both operands via LDS needs ~116 B/cyc — structurally
// over the port. Fix: repack x into A'[r5][h][kc][l31] so A-fragments are loaded
// straight from global (L1-dedup'd across the 4 waves sharing wm) as perfectly
// coalesced 1KB global_load_dwordx4, double-buffered in registers one half ahead.
// LDS holds ONLY B (4-slot ring, counted vmcnt, never 0 in main loop).
// 256x256 tile, 8 waves 2Mx4N, wave tile 128x64.

#define M_DIM 8192
#define K_DIM 4096
#define N_DIM 4096
#define KB2   (K_DIM / 2)      // packed bytes per row = 2048
#define HALFB 64               // bytes per row per K-half (128 k-elems)
#define NH    (KB2 / HALFB)    // 32 K-halves
#define SLOTB (256 * HALFB)    // B half-tile = 16 KB; 4-slot ring = 64 KB

typedef int   v4i  __attribute__((ext_vector_type(4)));
typedef int   v8i  __attribute__((ext_vector_type(8)));
typedef float v16f __attribute__((ext_vector_type(16)));

__device__ __forceinline__ unsigned int nib4(float x) {
    // fp4 e2m1: +1.0 -> 0b0010, -1.0 -> 0b1010, 0 -> 0b0000
    return x > 0.0f ? 0x2u : (x < 0.0f ? 0xAu : 0x0u);
}

// ---- fused pack: blocks [0, 32768) pack x -> A'; blocks [32768, 34816) pack wT ----
// A' layout: granule(r5, h, kc, l31) at byte ((r5*32 + h)*... precisely:
//   r5 = m>>5 (32-row block), h = K-half, kc = 16B k-granule (0..3), l31 = m&31.
//   byte offset = r5*65536 + h*2048 + kc*512 + l31*16.
// A GEMM wave reads granules {l31=0..31} x {kc=2ks+lhi} as ONE contiguous 1KB
// global_load_dwordx4 per (tm, ks).
__global__ __launch_bounds__(256) void pack_both(const float* __restrict__ x,
                                                 unsigned short* __restrict__ xq,
                                                 const float* __restrict__ w,
                                                 unsigned char* __restrict__ wT) {
    if (blockIdx.x < 32768u) {
        // dst-ordered: thread d writes ushort d of A' (fully coalesced store);
        // source = 4 consecutive floats of row m = r5*32+l31 at kbyte h*64+kc*16+2*b2.
        unsigned d   = blockIdx.x * 256 + threadIdx.x;   // 0 .. 2^23-1
        unsigned r5  = d >> 15;
        unsigned h   = (d >> 10) & 31;
        unsigned kc  = (d >> 8) & 3;
        unsigned l31 = (d >> 3) & 31;
        unsigned b2  = d & 7;
        size_t   m   = (size_t)r5 * 32 + l31;
        float4 f = ((const float4*)x)[m * 1024 + h * 32 + kc * 8 + b2];
        unsigned v = nib4(f.x) | (nib4(f.y) << 4) | (nib4(f.z) << 8) | (nib4(f.w) << 12);
        xq[d] = (unsigned short)v;
        return;
    }
    // pack wT: w[k][n] f32 -> wT[n][k/2] nibbles, 64k x 128n tile via LDS
    __shared__ unsigned char sT[64][132];
    const unsigned id = blockIdx.x - 32768u;
    const int t  = threadIdx.x;
    const int n0 = (int)(id & 31) * 128;
    const int kb = (int)(id >> 5);
    const int k0 = kb * 64;

    const int cq = t & 31;   // float4 column
    const int r0 = t >> 5;   // 0..7
#pragma unroll
    for (int p = 0; p < 8; ++p) {
        int r = r0 + 8 * p;
        float4 f = *(const float4*)(w + (size_t)(k0 + r) * N_DIM + n0 + cq * 4);
        uchar4 c;
        c.x = (unsigned char)nib4(f.x);
        c.y = (unsigned char)nib4(f.y);
        c.z = (unsigned char)nib4(f.z);
        c.w = (unsigned char)nib4(f.w);
        *(uchar4*)(&sT[r][cq * 4]) = c;
    }
    __syncthreads();

    const int n  = t >> 1;   // 0..127
    const int kq = t & 1;    // 32-k chunk
    union { unsigned char b[16]; int4 v; } u;
#pragma unroll
    for (int j = 0; j < 16; ++j) {
        unsigned lo = sT[kq * 32 + 2 * j][n];
        unsigned hi = sT[kq * 32 + 2 * j + 1][n];
        u.b[j] = (unsigned char)(lo | (hi << 4));
    }
    *(int4*)(wT + (size_t)(n0 + n) * KB2 + (size_t)kb * 32 + kq * 16) = u.v;
}

__device__ __forceinline__ v8i widen(v4i x) {
    v8i r;
    r[0] = x[0]; r[1] = x[1]; r[2] = x[2]; r[3] = x[3];
    r[4] = 0; r[5] = 0; r[6] = 0; r[7] = 0;
    return r;
}

// async global -> LDS, 16 bytes per lane (dest must be wave-uniform base + lane*16)
__device__ __forceinline__ void gload16(const unsigned char* g, unsigned char* l) {
    __builtin_amdgcn_global_load_lds(
        (__attribute__((address_space(1))) void*)(void*)g,
        (__attribute__((address_space(3))) void*)l, 16, 0, 0);
}

// 8-MFMA cluster; KS must be a literal (static register indexing).
#define CLUSTER(AU, KS, BB)                                              \
    do {                                                                 \
        __builtin_amdgcn_s_setprio(1);                                   \
        _Pragma("unroll")                                                \
        for (int tm_ = 0; tm_ < 4; ++tm_)                                \
            _Pragma("unroll")                                            \
            for (int tn_ = 0; tn_ < 2; ++tn_)                            \
                acc[tm_][tn_] = __builtin_amdgcn_mfma_scale_f32_32x32x64_f8f6f4( \
                    widen(AU[(KS) * 4 + tm_]), widen(BB[tn_]), acc[tm_][tn_],    \
                    4, 4, 0, 0x7F7F7F7F, 0, 0x7F7F7F7F);                 \
        __builtin_amdgcn_s_setprio(0);                                   \
    } while (0)

// One K-half: read B ks0 | prefetch A(h+1) | stage B(h+3) | mfma ks0 | read B ks1
// | mfma ks1 | counted vmcnt | barrier. VMC literal = allowed in-flight vmem ops.
#define BODY(H, AU, AF, DOA, DOS, VMC, DOBAR)                            \
    do {                                                                 \
        const unsigned char* sB_ = lds + ((H) & 3) * SLOTB;              \
        v4i bb0_[2], bb1_[2];                                            \
        bb0_[0] = *(const v4i*)(sB_ + offB[0][0]);                       \
        bb0_[1] = *(const v4i*)(sB_ + offB[0][1]);                       \
        if (DOA) loadA(AF, (H) + 1);                                     \
        if (DOS) stageB((H) + 3);                                        \
        CLUSTER(AU, 0, bb0_);                                            \
        bb1_[0] = *(const v4i*)(sB_ + offB[1][0]);                       \
        bb1_[1] = *(const v4i*)(sB_ + offB[1][1]);                       \
        CLUSTER(AU, 1, bb1_);                                            \
        asm volatile("s_waitcnt vmcnt(" #VMC ")" ::: "memory");          \
        if (DOBAR) __builtin_amdgcn_s_barrier();                         \
    } while (0)

// ---- fp4 MFMA GEMM: C[M,N] = A' * B^T ----
// B LDS half-tile: row r (0..255), k-granule kc at byte (r>>1)*128 + slot*16,
// slot = ((r&1)*4 | kc) ^ ((r>>1)&7) — conflict-optimal frag reads; staging's
// global source is pre-permuted so global_load_lds' linear dest yields it.
__global__ __launch_bounds__(512, 2) void bgemm_fp4(const unsigned char* __restrict__ A,
                                                    const unsigned char* __restrict__ B,
                                                    float* __restrict__ C) {
    __shared__ __align__(16) unsigned char lds[4 * SLOTB];   // 64 KB B ring

    const int tid  = threadIdx.x;
    const int lane = tid & 63;
    const int wave = tid >> 6;   // 0..7
    const int wm   = wave >> 2;  // 0..1 (M)
    const int wn   = wave & 3;   // 0..3 (N)
    const int l31  = lane & 31;
    const int lhi  = lane >> 5;

    // Bijective XCD chunk swizzle: 512 blocks = 8 XCDs x 64.
    const int id = (int)blockIdx.x;
    const int sw = (id & 7) * 64 + (id >> 3);
    const int bx = sw & 15;      // N tile (16)
    const int by = sw >> 4;      // M tile (32)
    const int n0 = bx * 256;

    v16f acc[4][2] = {};

    // B staging: per thread 2 granules per half: g = i*512 + tid (of 1024).
    const unsigned char* gBsrc[2];
    int dstOff[2];
#pragma unroll
    for (int i = 0; i < 2; ++i) {
        int g   = i * 512 + tid;
        int q   = g >> 3;
        int t   = (g & 7) ^ (q & 7);
        int row = 2 * q + (t >> 2);
        int kc  = t & 3;
        gBsrc[i] = B + (size_t)(n0 + row) * KB2 + kc * 16;
        dstOff[i] = g * 16;
    }

    // B fragment read offsets: ks (0..1), lane granule kc = 2*ks + lhi.
    int offB[2][2];
#pragma unroll
    for (int ks = 0; ks < 2; ++ks) {
        const int kc = 2 * ks + lhi;
#pragma unroll
        for (int tn = 0; tn < 2; ++tn) {
            int r    = wn * 64 + tn * 32 + l31;
            int q    = r >> 1;
            int slot = (((r & 1) << 2) | kc) ^ (q & 7);
            offB[ks][tn] = q * 128 + slot * 16;
        }
    }

    // A fragment base pointers (A' layout): frag (tm, ks, h) is the 16B at
    // gA[tm] + h*2048 + ks*1024 — contiguous 1KB per wave-instruction.
    const unsigned char* gA[4];
#pragma unroll
    for (int tm = 0; tm < 4; ++tm)
        gA[tm] = A + ((size_t)(by * 8 + wm * 4 + tm) << 16) + lhi * 512 + l31 * 16;

    auto stageB = [&](int h) {
        unsigned char* s = lds + (h & 3) * SLOTB;
        const size_t ko = (size_t)h * HALFB;
        gload16(gBsrc[0] + ko, s + dstOff[0]);   // 2 vmcnt ops total
        gload16(gBsrc[1] + ko, s + dstOff[1]);
    };

    v4i aA[8], aB[8];   // A frags, double-buffered by half; [ks*4+tm], static idx
    auto loadA = [&](v4i (&R)[8], int h) {
#pragma unroll
        for (int tm = 0; tm < 4; ++tm) {
            R[tm]     = *(const v4i*)(gA[tm] + (size_t)h * 2048);          // ks0
            R[4 + tm] = *(const v4i*)(gA[tm] + (size_t)h * 2048 + 1024);   // ks1
        }
    };

    // Prologue: B halves 0..2 staged (6 ops), A half 0 loaded (8 ops).
    // vmcnt(12) leaves B1,B2,A0 in flight; forces B0 -> barrier publishes it.
    stageB(0); stageB(1); stageB(2);
    loadA(aA, 0);
    asm volatile("s_waitcnt vmcnt(12)" ::: "memory");
    __builtin_amdgcn_s_barrier();

    // Steady state at BODY(h)'s wait: in flight = B(h+2)[2] + A(h+1)[8] + B(h+3)[2]
    // = 12; B(h+1) is older and forced done -> published by the barrier.
    // (Compiler's own vmcnt for AU-use inside the body forces A(h) and everything
    // older, so the ring slots are race-free: slot (h+3)&3 was last read at h-1,
    // whose ds_reads retired before the h-1 barrier.)
#pragma unroll 1
    for (int h = 0; h < NH - 4; h += 2) {     // bodies 0..27
        BODY(h,     aA, aB, 1, 1, 12, 1);
        BODY(h + 1, aB, aA, 1, 1, 12, 1);
    }
    BODY(28, aA, aB, 1, 1, 12, 1);            // stages B31; loads A29
    BODY(29, aB, aA, 1, 0, 10, 1);            // loads A30; allow A30+B31
    BODY(30, aA, aB, 1, 0, 8, 1);             // loads A31; allow A31, force B31
    BODY(31, aB, aA, 0, 0, 0, 0);

    // Epilogue: C/D 32x32 layout: col = lane&31, row = (r&3) + 8*(r>>2) + 4*lhi.
    const int m0 = by * 256;
#pragma unroll
    for (int tm = 0; tm < 4; ++tm) {
#pragma unroll
        for (int tn = 0; tn < 2; ++tn) {
            const int col  = n0 + wn * 64 + tn * 32 + l31;
            const int rowb = m0 + wm * 128 + tm * 32 + 4 * lhi;
#pragma unroll
            for (int r = 0; r < 16; ++r) {
                int row = rowb + (r & 3) + 8 * (r >> 2);
                __builtin_nontemporal_store(acc[tm][tn][r], &C[(size_t)row * N_DIM + col]);
            }
        }
    }
}

extern "C" void kernel_launch(void* const* d_in, const int* in_sizes, int n_in,
                              void* d_out, int out_size, void* d_ws, size_t ws_size,
                              hipStream_t stream) {
    const float* x = (const float*)d_in[0];   // [8192, 4096]
    const float* w = (const float*)d_in[1];   // [4096, 4096]
    float* out = (float*)d_out;               // [8192, 4096]

    unsigned char* xq = (unsigned char*)d_ws;                 // 16 MB packed A'
    unsigned char* wq = xq + (size_t)M_DIM * KB2;             // 8 MB packed wT

    // 32768 blocks pack x + 2048 blocks pack wT, one dispatch
    pack_both<<<dim3(32768 + 2048), dim3(256), 0, stream>>>(
        x, (unsigned short*)xq, w, wq);
    bgemm_fp4<<<dim3((M_DIM / 256) * (N_DIM / 256)), dim3(512), 0, stream>>>(xq, wq, out);
}

// Round 5
// 325.382 us; speedup vs baseline: 1.0404x; 1.0404x over previous
//
#include <hip/hip_runtime.h>

// BinaryDense: out = sign(x) @ sign(w). x[8192,4096] f32, w[4096,4096] f32, out f32.
// fp4 e2m1 nibble encoding {-1,0,+1} = {0xA,0x0,0x2}; MX-scaled fp4 MFMA (scales=1.0).
// Round 8: faithful m201 8-phase port. R4-R6 coarse schedules all plateaued at
// ~83us (the measured "2-phase plateau"); R7 (A from L1) regressed (TA-bound).
// Structure: per phase {6 ds_read + 2 global_load_lds -> barrier -> lgkmcnt(0)
// + sched_barrier -> setprio(1) 8 MFMA setprio(0) -> counted vmcnt -> barrier},
// 2 phases per K-half, 4-slot LDS ring (32 KB slots, 128 KB), stage 3 halves
// ahead, vmcnt(8) once per half (never 0 in main loop).
// 256x256 tile, 8 waves 2Mx4N, wave tile 128x64, pre-swizzled gload source.

#define M_DIM 8192
#define K_DIM 4096
#define N_DIM 4096
#define KB2   (K_DIM / 2)      // packed bytes per row = 2048
#define HALFB 64               // bytes per row per K-half (128 k-elems)
#define NH    (KB2 / HALFB)    // 32 K-halves
#define ATILE (256 * HALFB)    // one operand half-tile = 16 KB
#define SLOTB (2 * ATILE)      // ring slot (A+B) = 32 KB; 4 slots = 128 KB

typedef int   v4i  __attribute__((ext_vector_type(4)));
typedef int   v8i  __attribute__((ext_vector_type(8)));
typedef float v16f __attribute__((ext_vector_type(16)));

__device__ __forceinline__ unsigned int nib4(float x) {
    // fp4 e2m1: +1.0 -> 0b0010, -1.0 -> 0b1010, 0 -> 0b0000
    return x > 0.0f ? 0x2u : (x < 0.0f ? 0xAu : 0x0u);
}

// ---- fused pack: blocks [0, 32768) pack x; blocks [32768, 34816) pack wT ----
__global__ __launch_bounds__(256) void pack_both(const float* __restrict__ x,
                                                 unsigned short* __restrict__ xq,
                                                 const float* __restrict__ w,
                                                 unsigned char* __restrict__ wT) {
    if (blockIdx.x < 32768u) {
        // pack x: 4 floats -> 4 nibbles (one ushort) per thread
        size_t t = (size_t)blockIdx.x * 256 + threadIdx.x;
        float4 f = ((const float4*)x)[t];
        unsigned int v = nib4(f.x) | (nib4(f.y) << 4) | (nib4(f.z) << 8) | (nib4(f.w) << 12);
        xq[t] = (unsigned short)v;
        return;
    }
    // pack wT: w[k][n] f32 -> wT[n][k/2] nibbles, 64k x 128n tile via LDS
    __shared__ unsigned char sT[64][132];
    const unsigned id = blockIdx.x - 32768u;
    const int t  = threadIdx.x;
    const int n0 = (int)(id & 31) * 128;
    const int kb = (int)(id >> 5);
    const int k0 = kb * 64;

    const int cq = t & 31;   // float4 column
    const int r0 = t >> 5;   // 0..7
#pragma unroll
    for (int p = 0; p < 8; ++p) {
        int r = r0 + 8 * p;
        float4 f = *(const float4*)(w + (size_t)(k0 + r) * N_DIM + n0 + cq * 4);
        uchar4 c;
        c.x = (unsigned char)nib4(f.x);
        c.y = (unsigned char)nib4(f.y);
        c.z = (unsigned char)nib4(f.z);
        c.w = (unsigned char)nib4(f.w);
        *(uchar4*)(&sT[r][cq * 4]) = c;
    }
    __syncthreads();

    const int n  = t >> 1;   // 0..127
    const int kq = t & 1;    // 32-k chunk
    union { unsigned char b[16]; int4 v; } u;
#pragma unroll
    for (int j = 0; j < 16; ++j) {
        unsigned lo = sT[kq * 32 + 2 * j][n];
        unsigned hi = sT[kq * 32 + 2 * j + 1][n];
        u.b[j] = (unsigned char)(lo | (hi << 4));
    }
    *(int4*)(wT + (size_t)(n0 + n) * KB2 + (size_t)kb * 32 + kq * 16) = u.v;
}

__device__ __forceinline__ v8i widen(v4i x) {
    v8i r;
    r[0] = x[0]; r[1] = x[1]; r[2] = x[2]; r[3] = x[3];
    r[4] = 0; r[5] = 0; r[6] = 0; r[7] = 0;
    return r;
}

// async global -> LDS, 16 bytes per lane (dest must be wave-uniform base + lane*16)
__device__ __forceinline__ void gload16(const unsigned char* g, unsigned char* l) {
    __builtin_amdgcn_global_load_lds(
        (__attribute__((address_space(1))) void*)(void*)g,
        (__attribute__((address_space(3))) void*)l, 16, 0, 0);
}

// One phase (half H, k-step KS): m201 template skeleton.
//   6 ds_read_b128 (this phase's frags) | 2 global_load_lds (stage half H+3)
//   | s_barrier | lgkmcnt(0)+sched_barrier | setprio(1) 8 MFMA setprio(0)
//   | [counted vmcnt] | s_barrier
#define PHASE(H, KS, DOS, DOW, VMC, DOBAR)                               \
    do {                                                                 \
        const unsigned char* sA_ = lds + ((H) & 3) * SLOTB;              \
        const unsigned char* sB_ = sA_ + ATILE;                          \
        v4i a_[4], b_[2];                                                \
        a_[0] = *(const v4i*)(sA_ + offA[KS][0]);                        \
        a_[1] = *(const v4i*)(sA_ + offA[KS][1]);                        \
        a_[2] = *(const v4i*)(sA_ + offA[KS][2]);                        \
        a_[3] = *(const v4i*)(sA_ + offA[KS][3]);                        \
        b_[0] = *(const v4i*)(sB_ + offB[KS][0]);                        \
        b_[1] = *(const v4i*)(sB_ + offB[KS][1]);                        \
        if (DOS) {                                                       \
            unsigned char* st_ = lds + (((H) + 3) & 3) * SLOTB;          \
            const size_t ko_ = (size_t)((H) + 3) * HALFB;                \
            gload16(gAsrc[KS] + ko_, st_ + dstOff[KS]);                  \
            gload16(gBsrc[KS] + ko_, st_ + ATILE + dstOff[KS]);          \
        }                                                                \
        __builtin_amdgcn_s_barrier();                                    \
        asm volatile("s_waitcnt lgkmcnt(0)" ::: "memory");               \
        __builtin_amdgcn_sched_barrier(0);                               \
        __builtin_amdgcn_s_setprio(1);                                   \
        _Pragma("unroll")                                                \
        for (int tm_ = 0; tm_ < 4; ++tm_)                                \
            _Pragma("unroll")                                            \
            for (int tn_ = 0; tn_ < 2; ++tn_)                            \
                acc[tm_][tn_] = __builtin_amdgcn_mfma_scale_f32_32x32x64_f8f6f4( \
                    widen(a_[tm_]), widen(b_[tn_]), acc[tm_][tn_],       \
                    4, 4, 0, 0x7F7F7F7F, 0, 0x7F7F7F7F);                 \
        __builtin_amdgcn_s_setprio(0);                                   \
        if (DOW) asm volatile("s_waitcnt vmcnt(" #VMC ")" ::: "memory"); \
        if (DOBAR) __builtin_amdgcn_s_barrier();                         \
    } while (0)

// ---- fp4 MFMA GEMM: C[M,N] = A * B^T, A/B packed nibbles K-major ----
// LDS half-tile layout: row r (0..255), k-granule kc (0..3, 16 B each) at byte
// (r>>1)*128 + slot*16, slot = ((r&1)*4 | kc) ^ ((r>>1)&7) — uniform 8-word/bank
// frag reads. Staging granule g (linear LDS dest g*16): q=g>>3, t=(g&7)^(q&7),
// src row = 2q+(t>>2), kc = t&3 — inverse permutation pre-applied to the global
// source so global_load_lds' linear dest yields this layout.
__global__ __launch_bounds__(512, 2) void bgemm_fp4(const unsigned char* __restrict__ A,
                                                    const unsigned char* __restrict__ B,
                                                    float* __restrict__ C) {
    __shared__ __align__(16) unsigned char lds[4 * SLOTB];   // 128 KB ring

    const int tid  = threadIdx.x;
    const int lane = tid & 63;
    const int wave = tid >> 6;   // 0..7
    const int wm   = wave >> 2;  // 0..1 (M)
    const int wn   = wave & 3;   // 0..3 (N)
    const int l31  = lane & 31;
    const int lhi  = lane >> 5;

    // Bijective XCD chunk swizzle: 512 blocks = 8 XCDs x 64.
    const int id = (int)blockIdx.x;
    const int sw = (id & 7) * 64 + (id >> 3);
    const int bx = sw & 15;      // N tile (16)
    const int by = sw >> 4;      // M tile (32)
    const int m0 = by * 256;
    const int n0 = bx * 256;

    v16f acc[4][2] = {};

    // Staging: per thread 2 granules of A and 2 of B per half: g = i*512 + tid.
    const unsigned char* gAsrc[2];
    const unsigned char* gBsrc[2];
    int dstOff[2];
#pragma unroll
    for (int i = 0; i < 2; ++i) {
        int g   = i * 512 + tid;       // 0..1023
        int q   = g >> 3;              // rowpair 0..127
        int t   = (g & 7) ^ (q & 7);
        int row = 2 * q + (t >> 2);
        int kc  = t & 3;
        gAsrc[i] = A + (size_t)(m0 + row) * KB2 + kc * 16;
        gBsrc[i] = B + (size_t)(n0 + row) * KB2 + kc * 16;
        dstOff[i] = g * 16;
    }

    // Fragment read offsets: k-step ks (0..1), lane granule kc = 2*ks + lhi.
    int offA[2][4], offB[2][2];
#pragma unroll
    for (int ks = 0; ks < 2; ++ks) {
        const int kc = 2 * ks + lhi;
#pragma unroll
        for (int tm = 0; tm < 4; ++tm) {
            int r    = wm * 128 + tm * 32 + l31;
            int q    = r >> 1;
            int slot = (((r & 1) << 2) | kc) ^ (q & 7);
            offA[ks][tm] = q * 128 + slot * 16;
        }
#pragma unroll
        for (int tn = 0; tn < 2; ++tn) {
            int r    = wn * 64 + tn * 32 + l31;
            int q    = r >> 1;
            int slot = (((r & 1) << 2) | kc) ^ (q & 7);
            offB[ks][tn] = q * 128 + slot * 16;
        }
    }

    auto stage_full = [&](int h) {
        unsigned char* s = lds + (h & 3) * SLOTB;
        const size_t ko = (size_t)h * HALFB;
#pragma unroll
        for (int i = 0; i < 2; ++i) {
            gload16(gAsrc[i] + ko, s + dstOff[i]);            // 4 vmcnt ops total
            gload16(gBsrc[i] + ko, s + ATILE + dstOff[i]);
        }
    };

    // Prologue: halves 0..2 staged (12 ops); vmcnt(8) forces half 0; barrier
    // publishes it (each wave only waits its OWN DMA; barrier makes all visible).
    stage_full(0); stage_full(1); stage_full(2);
    asm volatile("s_waitcnt vmcnt(8)" ::: "memory");
    __builtin_amdgcn_s_barrier();

    // Steady state (end of half h, after vmcnt(8)): in flight <= {h+2, h+3} (8 ops),
    // h+1 and older complete -> readable next half. Stage h+3 writes slot (h-1)&3,
    // whose last reads retired before half h-1's final barrier. Drain: end of 28
    // forces 29 via vmcnt(8) (12 in flight); end of 29 -> vmcnt(4); 30 -> vmcnt(0).
#pragma unroll 1
    for (int h = 0; h < NH - 3; ++h) {                        // h = 0..28
        PHASE(h, 0, 1, 0, 0, 1);
        PHASE(h, 1, 1, 1, 8, 1);
    }
    PHASE(NH - 3, 0, 0, 0, 0, 1);
    PHASE(NH - 3, 1, 0, 1, 4, 1);
    PHASE(NH - 2, 0, 0, 0, 0, 1);
    PHASE(NH - 2, 1, 0, 1, 0, 1);
    PHASE(NH - 1, 0, 0, 0, 0, 1);
    PHASE(NH - 1, 1, 0, 0, 0, 0);

    // Epilogue: C/D 32x32 layout: col = lane&31, row = (r&3) + 8*(r>>2) + 4*lhi.
    // Nontemporal: C is streamed once; keep packed operands resident in L2/L3.
#pragma unroll
    for (int tm = 0; tm < 4; ++tm) {
#pragma unroll
        for (int tn = 0; tn < 2; ++tn) {
            const int col  = n0 + wn * 64 + tn * 32 + l31;
            const int rowb = m0 + wm * 128 + tm * 32 + 4 * lhi;
#pragma unroll
            for (int r = 0; r < 16; ++r) {
                int row = rowb + (r & 3) + 8 * (r >> 2);
                __builtin_nontemporal_store(acc[tm][tn][r], &C[(size_t)row * N_DIM + col]);
            }
        }
    }
}

extern "C" void kernel_launch(void* const* d_in, const int* in_sizes, int n_in,
                              void* d_out, int out_size, void* d_ws, size_t ws_size,
                              hipStream_t stream) {
    const float* x = (const float*)d_in[0];   // [8192, 4096]
    const float* w = (const float*)d_in[1];   // [4096, 4096]
    float* out = (float*)d_out;               // [8192, 4096]

    unsigned char* xq = (unsigned char*)d_ws;                 // 16 MB packed x
    unsigned char* wq = xq + (size_t)M_DIM * KB2;             // 8 MB packed wT

    // 32768 blocks pack x + 2048 blocks pack wT, one dispatch
    pack_both<<<dim3(32768 + 2048), dim3(256), 0, stream>>>(
        x, (unsigned short*)xq, w, wq);
    bgemm_fp4<<<dim3((M_DIM / 256) * (N_DIM / 256)), dim3(512), 0, stream>>>(xq, wq, out);
}